// Round 14
// baseline (612.859 us; speedup 1.0000x reference)
//
#include <hip/hip_runtime.h>
#include <hip/hip_bf16.h>

#define HID 256
#define HHALF 128

typedef unsigned short u16;
typedef __attribute__((ext_vector_type(8))) short bf16x8;
typedef __attribute__((ext_vector_type(4))) float f32x4;

__device__ __forceinline__ float bf2f(unsigned int u) {
    unsigned int x = (u & 0xffffu) << 16;
    union { unsigned int i; float f; } c; c.i = x; return c.f;
}
__device__ __forceinline__ float lof(unsigned u) {
    union { unsigned i; float f; } c; c.i = u << 16; return c.f;
}
__device__ __forceinline__ float hif(unsigned u) {
    union { unsigned i; float f; } c; c.i = u & 0xffff0000u; return c.f;
}
__device__ __forceinline__ u16 f2bf(float f) {
    __hip_bfloat16 h = __float2bfloat16(f);   // RNE
    union { __hip_bfloat16 h; u16 u; } c; c.h = h; return c.u;
}

// async global->LDS, 16B per lane; lds dest is wave-uniform base + lane*16
__device__ __forceinline__ void gload16(const u16* g, u16* l) {
    __builtin_amdgcn_global_load_lds(
        (const __attribute__((address_space(1))) void*)g,
        (__attribute__((address_space(3))) void*)l, 16, 0, 0);
}

// ---------------- CSR build ----------------
__global__ void k_count(const int* __restrict__ dst, int* __restrict__ cnt, int E) {
    int i = blockIdx.x * blockDim.x + threadIdx.x;
    if (i < E) atomicAdd(&cnt[dst[i]], 1);
}

__global__ void k_scan_block(const int* __restrict__ cnt, int* __restrict__ bsum, int n) {
    __shared__ int sd[256];
    int tid = threadIdx.x;
    int i = blockIdx.x * 256 + tid;
    int v = (i < n) ? cnt[i] : 0;
    sd[tid] = v; __syncthreads();
    for (int s = 128; s > 0; s >>= 1) {
        if (tid < s) sd[tid] += sd[tid + s];
        __syncthreads();
    }
    if (tid == 0) bsum[blockIdx.x] = sd[0];
}

__global__ void k_scan_top(int* __restrict__ bsum, int nb) {
    __shared__ int sd[512];
    int t = threadIdx.x;
    int v = (t < nb) ? bsum[t] : 0;
    sd[t] = v; __syncthreads();
    for (int s = 1; s < 512; s <<= 1) {
        int x = (t >= s) ? sd[t - s] : 0;
        __syncthreads();
        sd[t] += x;
        __syncthreads();
    }
    if (t < nb) bsum[t] = sd[t] - v;  // exclusive
}

__global__ void k_scan_down(const int* __restrict__ cnt, const int* __restrict__ boff,
                            int* __restrict__ row_off, int n, int total) {
    __shared__ int sd[256];
    int tid = threadIdx.x;
    int i = blockIdx.x * 256 + tid;
    int v = (i < n) ? cnt[i] : 0;
    sd[tid] = v; __syncthreads();
    for (int s = 1; s < 256; s <<= 1) {
        int x = (tid >= s) ? sd[tid - s] : 0;
        __syncthreads();
        sd[tid] += x;
        __syncthreads();
    }
    if (i < n) row_off[i] = boff[blockIdx.x] + sd[tid] - v;
    if (i == 0) row_off[n] = total;
}

__global__ void k_scatter(const int* __restrict__ src, const int* __restrict__ dst,
                          const int* __restrict__ row_off, int* __restrict__ fill,
                          int* __restrict__ col, int E) {
    int i = blockIdx.x * blockDim.x + threadIdx.x;
    if (i < E) {
        int d = dst[i];
        int p = atomicAdd(&fill[d], 1);
        col[row_off[d] + p] = src[i];
    }
}

// ---------------- conversions ----------------
__global__ void k_f2b(const float* __restrict__ in, u16* __restrict__ o, int total4) {
    int i = blockIdx.x * blockDim.x + threadIdx.x;
    if (i >= total4) return;
    float4 v = *(const float4*)&in[(size_t)i * 4];
    uint2 p;
    p.x = (unsigned)f2bf(v.x) | ((unsigned)f2bf(v.y) << 16);
    p.y = (unsigned)f2bf(v.z) | ((unsigned)f2bf(v.w) << 16);
    *(uint2*)&o[(size_t)i * 4] = p;
}

// all weight transposes in one launch: mats 0..L-1 = Ws, L..2L-1 = Wn, 2L = nd_W1
__global__ void k_wt_all(const float* __restrict__ Ws, const float* __restrict__ Wn,
                         const float* __restrict__ ndW1,
                         u16* __restrict__ WsT, u16* __restrict__ WnT,
                         u16* __restrict__ ndW1T, int L) {
    int idx = blockIdx.x * 256 + threadIdx.x;
    int mat = idx >> 16;            // 65536 elems per 256x256 slot
    int r = idx & 65535;
    int k = r >> 8, c = r & 255;
    if (mat < L) {
        WsT[(size_t)mat * 65536 + c * 256 + k] = f2bf(Ws[(size_t)mat * 65536 + k * 256 + c]);
    } else if (mat < 2 * L) {
        int l = mat - L;
        WnT[(size_t)l * 65536 + c * 256 + k] = f2bf(Wn[(size_t)l * 65536 + k * 256 + c]);
    } else {
        if (c < HHALF) ndW1T[c * 256 + k] = f2bf(ndW1[k * HHALF + c]);
    }
}

// ---------------- mean aggregation (bf16 in/out, fp32 accum) ----------------
// 4 waves/block, one node per wave; halves take alternate neighbors; unroll x8
// main loop + single clamped-load masked tail (keeps 4 loads in flight).
__global__ __launch_bounds__(256) void k_agg(
    const u16* __restrict__ h, const int* __restrict__ row_off,
    const int* __restrict__ col, u16* __restrict__ msg, int n) {
    int node = blockIdx.x * 4 + (threadIdx.x >> 6);
    if (node >= n) return;
    int lane = threadIdx.x & 63;
    int half = lane >> 5;
    int t = lane & 31;              // owns channels t*8 .. t*8+7
    int s0 = row_off[node], s1 = row_off[node + 1];
    float a0 = 0.f, a1 = 0.f, a2 = 0.f, a3 = 0.f;
    float a4 = 0.f, a5 = 0.f, a6 = 0.f, a7 = 0.f;
    int e = s0;
    for (; e + 8 <= s1; e += 8) {
        int c0 = col[e + half];
        int c1 = col[e + 2 + half];
        int c2 = col[e + 4 + half];
        int c3 = col[e + 6 + half];
        uint4 v0 = *(const uint4*)&h[(size_t)c0 * HID + t * 8];
        uint4 v1 = *(const uint4*)&h[(size_t)c1 * HID + t * 8];
        uint4 v2 = *(const uint4*)&h[(size_t)c2 * HID + t * 8];
        uint4 v3 = *(const uint4*)&h[(size_t)c3 * HID + t * 8];
        a0 += (lof(v0.x) + lof(v1.x)) + (lof(v2.x) + lof(v3.x));
        a1 += (hif(v0.x) + hif(v1.x)) + (hif(v2.x) + hif(v3.x));
        a2 += (lof(v0.y) + lof(v1.y)) + (lof(v2.y) + lof(v3.y));
        a3 += (hif(v0.y) + hif(v1.y)) + (hif(v2.y) + hif(v3.y));
        a4 += (lof(v0.z) + lof(v1.z)) + (lof(v2.z) + lof(v3.z));
        a5 += (hif(v0.z) + hif(v1.z)) + (hif(v2.z) + hif(v3.z));
        a6 += (lof(v0.w) + lof(v1.w)) + (lof(v2.w) + lof(v3.w));
        a7 += (hif(v0.w) + hif(v1.w)) + (hif(v2.w) + hif(v3.w));
    }
    if (e < s1) {
        int i0 = e + half, i1 = e + 2 + half, i2 = e + 4 + half, i3 = e + 6 + half;
        float w0 = (i0 < s1) ? 1.f : 0.f; int c0 = col[(i0 < s1) ? i0 : s0];
        float w1 = (i1 < s1) ? 1.f : 0.f; int c1 = col[(i1 < s1) ? i1 : s0];
        float w2 = (i2 < s1) ? 1.f : 0.f; int c2 = col[(i2 < s1) ? i2 : s0];
        float w3 = (i3 < s1) ? 1.f : 0.f; int c3 = col[(i3 < s1) ? i3 : s0];
        uint4 v0 = *(const uint4*)&h[(size_t)c0 * HID + t * 8];
        uint4 v1 = *(const uint4*)&h[(size_t)c1 * HID + t * 8];
        uint4 v2 = *(const uint4*)&h[(size_t)c2 * HID + t * 8];
        uint4 v3 = *(const uint4*)&h[(size_t)c3 * HID + t * 8];
        a0 = fmaf(w0, lof(v0.x), fmaf(w1, lof(v1.x), fmaf(w2, lof(v2.x), fmaf(w3, lof(v3.x), a0))));
        a1 = fmaf(w0, hif(v0.x), fmaf(w1, hif(v1.x), fmaf(w2, hif(v2.x), fmaf(w3, hif(v3.x), a1))));
        a2 = fmaf(w0, lof(v0.y), fmaf(w1, lof(v1.y), fmaf(w2, lof(v2.y), fmaf(w3, lof(v3.y), a2))));
        a3 = fmaf(w0, hif(v0.y), fmaf(w1, hif(v1.y), fmaf(w2, hif(v2.y), fmaf(w3, hif(v3.y), a3))));
        a4 = fmaf(w0, lof(v0.z), fmaf(w1, lof(v1.z), fmaf(w2, lof(v2.z), fmaf(w3, lof(v3.z), a4))));
        a5 = fmaf(w0, hif(v0.z), fmaf(w1, hif(v1.z), fmaf(w2, hif(v2.z), fmaf(w3, hif(v3.z), a5))));
        a6 = fmaf(w0, lof(v0.w), fmaf(w1, lof(v1.w), fmaf(w2, lof(v2.w), fmaf(w3, lof(v3.w), a6))));
        a7 = fmaf(w0, hif(v0.w), fmaf(w1, hif(v1.w), fmaf(w2, hif(v2.w), fmaf(w3, hif(v3.w), a7))));
    }
    a0 += __shfl_xor(a0, 32); a1 += __shfl_xor(a1, 32);
    a2 += __shfl_xor(a2, 32); a3 += __shfl_xor(a3, 32);
    a4 += __shfl_xor(a4, 32); a5 += __shfl_xor(a5, 32);
    a6 += __shfl_xor(a6, 32); a7 += __shfl_xor(a7, 32);
    if (half == 0) {
        int deg = s1 - s0;
        float inv = 1.0f / (float)(deg > 1 ? deg : 1);
        uint4 o;
        o.x = (unsigned)f2bf(a0 * inv) | ((unsigned)f2bf(a1 * inv) << 16);
        o.y = (unsigned)f2bf(a2 * inv) | ((unsigned)f2bf(a3 * inv) << 16);
        o.z = (unsigned)f2bf(a4 * inv) | ((unsigned)f2bf(a5 * inv) << 16);
        o.w = (unsigned)f2bf(a6 * inv) | ((unsigned)f2bf(a7 * inv) << 16);
        *(uint4*)&msg[(size_t)node * HID + t * 8] = o;
    }
}

// ---------------- bf16 MFMA GEMM: out = relu(A1@W1 [+ A2@W2] + bias) ----------------
// R9 geometry (128x256, 8 waves 2x4, BK=32, 3 gloads/step) + DOUBLE BUFFER with
// drain-after-MFMA: stage(kt+1) issued right after the single per-step barrier,
// flies while tile kt computes; next step's __syncthreads (vmcnt0+barrier) drains.
// No sched_barrier, no counted vmcnt (both proven harmful at 2-phase: R6/m141).
// XOR chunk swizzle both sides; swapped operands; fused row-dot epilogue.
__global__ __launch_bounds__(512) void k_gemm_bf(
    const u16* __restrict__ A1, const u16* __restrict__ W1t,
    const u16* __restrict__ A2, const u16* __restrict__ W2t,
    const float* __restrict__ bias, u16* __restrict__ out,
    int n, int ncols,
    const float* __restrict__ dotw, const float* __restrict__ dotb,
    float* __restrict__ dotout) {
    __shared__ __align__(16) u16 As[2][128 * 32];   // 2 x 8 KB
    __shared__ __align__(16) u16 Bs[2][256 * 32];   // 2 x 16 KB
    const int tid  = threadIdx.x;
    const int lane = tid & 63;
    const int w    = tid >> 6;           // 0..7
    const int wr   = w >> 2, wc = w & 3; // wave tile: rows wr*64+, cols wc*64+
    const int brow = blockIdx.x * 128;
    const int nkt  = A2 ? 16 : 8;        // BK=32 K-steps (8 per operand phase)

    f32x4 acc[4][4];
    #pragma unroll
    for (int m = 0; m < 4; ++m)
        #pragma unroll
        for (int q = 0; q < 4; ++q)
            acc[m][q] = (f32x4){0.f, 0.f, 0.f, 0.f};

    // staging addresses (R9-verified): per K-step add k0
    const int arow_t = w * 16 + (lane >> 2);         // A tile row this lane fetches
    int arow = brow + arow_t; if (arow >= n) arow = n - 1;
    const int ach = (lane & 3) ^ ((arow_t >> 1) & 3);
    const size_t abase = (size_t)arow * HID + ach * 8;
    const int As_off = (w * 16) * 32;                // wave-uniform

    const int brow0 = w * 32 + (lane >> 2);
    const int bch0  = (lane & 3) ^ ((brow0 >> 1) & 3);
    const size_t bbase0 = (size_t)brow0 * HID + bch0 * 8;
    const int Bs_off0 = (w * 32) * 32;
    const int brow1 = brow0 + 16;
    const int bch1  = (lane & 3) ^ ((brow1 >> 1) & 3);
    const size_t bbase1 = (size_t)brow1 * HID + bch1 * 8;
    const int Bs_off1 = (w * 32 + 16) * 32;

    const int lr = lane & 15;
    const int lq = lane >> 4;
    const int ph = lq ^ ((lr >> 1) & 3);  // read-side swizzled chunk

    auto stage = [&](int t) {
        const u16* A = (t < 8) ? A1 : A2;
        const u16* W = (t < 8) ? W1t : W2t;
        const int k0 = (t & 7) * 32;
        const int b = t & 1;
        gload16(A + abase + k0, &As[b][As_off]);
        gload16(W + bbase0 + k0, &Bs[b][Bs_off0]);
        gload16(W + bbase1 + k0, &Bs[b][Bs_off1]);
    };

    stage(0);
    for (int kt = 0; kt < nkt; ++kt) {
        __syncthreads();                  // vmcnt(0)+lgkm drain of stage(kt) + sync
        if (kt + 1 < nkt) stage(kt + 1);  // next tile flies under this tile's compute
        const int b = kt & 1;
        bf16x8 af[4], bg[4];
        #pragma unroll
        for (int m = 0; m < 4; ++m)
            af[m] = *(const bf16x8*)&As[b][(wr * 64 + m * 16 + lr) * 32 + ph * 8];
        #pragma unroll
        for (int q = 0; q < 4; ++q)
            bg[q] = *(const bf16x8*)&Bs[b][(wc * 64 + q * 16 + lr) * 32 + ph * 8];
        #pragma unroll
        for (int m = 0; m < 4; ++m)
            #pragma unroll
            for (int q = 0; q < 4; ++q)
                acc[m][q] = __builtin_amdgcn_mfma_f32_16x16x32_bf16(
                    bg[q], af[m], acc[m][q], 0, 0, 0);  // swapped: lane holds 4 cols of a row
    }

    // epilogue: row = brow+wr*64+m*16+lr; col = wc*64+q*16+lq*4+j
    #pragma unroll
    for (int m = 0; m < 4; ++m) {
        int row = brow + wr * 64 + m * 16 + lr;
        if (row >= n) continue;
        float dpart = 0.f;
        #pragma unroll
        for (int q = 0; q < 4; ++q) {
            int col = wc * 64 + q * 16 + lq * 4;
            if (col < ncols) {
                float4 bb = *(const float4*)&bias[col];
                float r0 = fmaxf(acc[m][q][0] + bb.x, 0.f);
                float r1 = fmaxf(acc[m][q][1] + bb.y, 0.f);
                float r2 = fmaxf(acc[m][q][2] + bb.z, 0.f);
                float r3 = fmaxf(acc[m][q][3] + bb.w, 0.f);
                if (out) {
                    uint2 o;
                    o.x = (unsigned)f2bf(r0) | ((unsigned)f2bf(r1) << 16);
                    o.y = (unsigned)f2bf(r2) | ((unsigned)f2bf(r3) << 16);
                    *(uint2*)&out[(size_t)row * ncols + col] = o;
                }
                if (dotout) {
                    float4 wv = *(const float4*)&dotw[col];
                    dpart += r0 * wv.x + r1 * wv.y + r2 * wv.z + r3 * wv.w;
                }
            }
        }
        if (dotout && (wc * 64 < ncols)) {
            dpart += __shfl_xor(dpart, 16);
            dpart += __shfl_xor(dpart, 32);
            if (lane < 16) {
                float add = dpart + ((wc == 0) ? dotb[0] : 0.f);
                atomicAdd(&dotout[row], add);
            }
        }
    }
}

// ---------------- node head: dotout[row] = relu(h@W1t+b1) . dotw + dotb ----------------
// R13-verified: dedicated 128x128 tile, 4 waves (2x2), 256 threads, BK=64, nkt=4.
__global__ __launch_bounds__(256) void k_ndhead(
    const u16* __restrict__ A1, const u16* __restrict__ W1t,
    const float* __restrict__ bias, int n,
    const float* __restrict__ dotw, const float* __restrict__ dotb,
    float* __restrict__ dotout) {
    __shared__ __align__(16) u16 As[128 * 64];   // 16 KB
    __shared__ __align__(16) u16 Bs[128 * 64];   // 16 KB
    const int tid  = threadIdx.x;
    const int lane = tid & 63;
    const int w    = tid >> 6;           // 0..3
    const int wr   = w >> 1, wc = w & 1;
    const int brow = blockIdx.x * 128;

    f32x4 acc[4][4];
    #pragma unroll
    for (int m = 0; m < 4; ++m)
        #pragma unroll
        for (int q = 0; q < 4; ++q)
            acc[m][q] = (f32x4){0.f, 0.f, 0.f, 0.f};

    // staging: 1024 A chunks + 1024 B chunks; thread handles 4 of each.
    size_t asrc[4], bsrc[4];
    u16 *adst[4], *bdst[4];
    #pragma unroll
    for (int i = 0; i < 4; ++i) {
        int s = tid + i * 256;           // chunk 0..1023
        int row = s >> 3;
        int ch = ((s & 7) ^ ((row >> 1) & 7)) * 8;
        int ar = brow + row; if (ar >= n) ar = n - 1;
        asrc[i] = (size_t)ar * HID + ch;
        bsrc[i] = (size_t)row * HID + ch;            // W1t rows 0..127 (stride 256)
        adst[i] = &As[(i * 256 + w * 64) * 8];       // wave-uniform
        bdst[i] = &Bs[(i * 256 + w * 64) * 8];
    }

    const int lr = lane & 15;
    const int lq = lane >> 4;
    const int swz = (lr >> 1) & 7;

    for (int kt = 0; kt < 4; ++kt) {
        const int k0 = kt * 64;
        __syncthreads();
        #pragma unroll
        for (int i = 0; i < 4; ++i) gload16(A1 + asrc[i] + k0, adst[i]);
        #pragma unroll
        for (int i = 0; i < 4; ++i) gload16(W1t + bsrc[i] + k0, bdst[i]);
        __syncthreads();
        #pragma unroll
        for (int ks = 0; ks < 2; ++ks) {
            const int ch = (ks * 4 + lq) ^ swz;
            bf16x8 af[4], bg[4];
            #pragma unroll
            for (int m = 0; m < 4; ++m)
                af[m] = *(const bf16x8*)&As[(wr * 64 + m * 16 + lr) * 64 + ch * 8];
            #pragma unroll
            for (int q = 0; q < 4; ++q)
                bg[q] = *(const bf16x8*)&Bs[(wc * 64 + q * 16 + lr) * 64 + ch * 8];
            #pragma unroll
            for (int m = 0; m < 4; ++m)
                #pragma unroll
                for (int q = 0; q < 4; ++q)
                    acc[m][q] = __builtin_amdgcn_mfma_f32_16x16x32_bf16(
                        bg[q], af[m], acc[m][q], 0, 0, 0);
        }
    }

    #pragma unroll
    for (int m = 0; m < 4; ++m) {
        int row = brow + wr * 64 + m * 16 + lr;
        if (row >= n) continue;
        float dpart = 0.f;
        #pragma unroll
        for (int q = 0; q < 4; ++q) {
            int col = wc * 64 + q * 16 + lq * 4;
            float4 bb = *(const float4*)&bias[col];
            float4 wv = *(const float4*)&dotw[col];
            dpart += fmaxf(acc[m][q][0] + bb.x, 0.f) * wv.x
                   + fmaxf(acc[m][q][1] + bb.y, 0.f) * wv.y
                   + fmaxf(acc[m][q][2] + bb.z, 0.f) * wv.z
                   + fmaxf(acc[m][q][3] + bb.w, 0.f) * wv.w;
        }
        dpart += __shfl_xor(dpart, 16);
        dpart += __shfl_xor(dpart, 32);
        if (lane < 16) {
            float add = dpart + ((wc == 0) ? dotb[0] : 0.f);
            atomicAdd(&dotout[row], add);
        }
    }
}

// ---------------- graph start offsets from sorted batch ----------------
__global__ void k_gstart(const int* __restrict__ batch, int* __restrict__ gstart, int n, int G) {
    int i = blockIdx.x * blockDim.x + threadIdx.x;
    if (i >= n) return;
    int b = batch[i];
    int bp = (i == 0) ? -1 : batch[i - 1];
    for (int g = bp + 1; g <= b; ++g) gstart[g] = i;
    if (i == n - 1) {
        for (int g = b + 1; g <= G; ++g) gstart[g] = n;
    }
}

// ---------------- per-graph max + softmax denom ----------------
__global__ void k_mdenom(const float* __restrict__ s, const int* __restrict__ gstart,
                         float* __restrict__ m, float* __restrict__ denom) {
    int g = blockIdx.x;
    int t = threadIdx.x;
    int i0 = gstart[g], i1 = gstart[g + 1];
    __shared__ float red[256];
    float mx = -INFINITY;
    for (int i = i0 + t; i < i1; i += 256) mx = fmaxf(mx, s[i]);
    red[t] = mx; __syncthreads();
    for (int st = 128; st; st >>= 1) {
        if (t < st) red[t] = fmaxf(red[t], red[t + st]);
        __syncthreads();
    }
    float gm = red[0];
    __syncthreads();
    float sm = 0.f;
    for (int i = i0 + t; i < i1; i += 256) sm += expf(s[i] - gm);
    red[t] = sm; __syncthreads();
    for (int st = 128; st; st >>= 1) {
        if (t < st) red[t] += red[t + st];
        __syncthreads();
    }
    if (t == 0) { m[g] = gm; denom[g] = red[0]; }
}

// ---------------- attention pooling with inline alpha ----------------
__global__ void k_pool(const u16* __restrict__ h, const float* __restrict__ sarr,
                       const float* __restrict__ marr, const float* __restrict__ denom,
                       const int* __restrict__ gstart, float* __restrict__ gpool) {
    int g = blockIdx.x, sp = blockIdx.y, t = threadIdx.x;
    int i0 = gstart[g], i1 = gstart[g + 1];
    int len = i1 - i0;
    int a = i0 + (int)((long long)len * sp / 16);
    int b = i0 + (int)((long long)len * (sp + 1) / 16);
    float dn = denom[g];
    float inv = (dn > 0.f) ? 1.0f / dn : 0.f;
    float mg = marr[g];
    float acc = 0.f;
    for (int i = a; i < b; ++i)
        acc += expf(sarr[i] - mg) * inv * bf2f(h[(size_t)i * HID + t]);
    if (acc != 0.f || sp == 0) atomicAdd(&gpool[g * HID + t], acc);
}

// ---------------- graph head ----------------
__global__ void k_ghead(const float* __restrict__ gpool, const float* __restrict__ W1,
                        const float* __restrict__ b1, const float* __restrict__ W2,
                        const float* __restrict__ b2, float* __restrict__ out) {
    int g = blockIdx.x, t = threadIdx.x;  // 128 threads
    __shared__ float row[HID];
    __shared__ float red[128];
    row[t] = gpool[g * HID + t];
    row[t + 128] = gpool[g * HID + t + 128];
    __syncthreads();
    float acc = 0.f;
    #pragma unroll 8
    for (int k = 0; k < HID; ++k) acc = fmaf(row[k], W1[k * HHALF + t], acc);
    float hid = fmaxf(acc + b1[t], 0.f);
    red[t] = hid * W2[t];
    __syncthreads();
    for (int st = 64; st; st >>= 1) {
        if (t < st) red[t] += red[t + st];
        __syncthreads();
    }
    if (t == 0) out[g] = red[0] + b2[0];
}

extern "C" void kernel_launch(void* const* d_in, const int* in_sizes, int n_in,
                              void* d_out, int out_size, void* d_ws, size_t ws_size,
                              hipStream_t stream) {
    const float* x      = (const float*)d_in[0];
    const int*   eidx   = (const int*)d_in[1];
    const int*   batch  = (const int*)d_in[2];
    const float* Ws     = (const float*)d_in[3];
    const float* Wn     = (const float*)d_in[4];
    const float* bs     = (const float*)d_in[5];
    const float* att_w  = (const float*)d_in[6];
    const float* att_b  = (const float*)d_in[7];
    const float* ne_W1  = (const float*)d_in[8];
    const float* ne_b1  = (const float*)d_in[9];
    const float* ne_W2  = (const float*)d_in[10];
    const float* ne_b2  = (const float*)d_in[11];
    const float* nd_W1  = (const float*)d_in[12];
    const float* nd_b1  = (const float*)d_in[13];
    const float* nd_W2  = (const float*)d_in[14];
    const float* nd_b2  = (const float*)d_in[15];
    float* out = (float*)d_out;

    const int N = in_sizes[2];
    const int E = in_sizes[1] / 2;
    const int L = in_sizes[3] / (HID * HID);
    const int G = out_size - N;

    const int* src = eidx;
    const int* dst = eidx + E;

    size_t off = 0;
    auto alloc = [&](size_t bytes) {
        void* p = (char*)d_ws + off;
        off += (bytes + 255) & ~(size_t)255;
        return p;
    };
    int*   cnt     = (int*)alloc((size_t)N * 4);
    int*   row_off = (int*)alloc((size_t)(N + 1) * 4);
    int*   fill    = (int*)alloc((size_t)N * 4);
    int*   col     = (int*)alloc((size_t)E * 4);
    int*   gstart  = (int*)alloc((size_t)(G + 1) * 4);
    int*   bsum    = (int*)alloc(1024 * 4);
    float* sarr    = (float*)alloc((size_t)N * 4);
    float* marr    = (float*)alloc((size_t)G * 4);
    float* denom   = (float*)alloc((size_t)G * 4);
    float* gpool   = (float*)alloc((size_t)G * HID * 4);
    u16*   xb      = (u16*)alloc((size_t)N * HID * 2);
    u16*   msgb    = (u16*)alloc((size_t)N * HID * 2);
    u16*   hb1     = (u16*)alloc((size_t)N * HID * 2);
    u16*   hb2     = (u16*)alloc((size_t)N * HID * 2);
    u16*   WsT     = (u16*)alloc((size_t)L * HID * HID * 2);
    u16*   WnT     = (u16*)alloc((size_t)L * HID * HID * 2);
    u16*   ndW1T   = (u16*)alloc((size_t)HID * HID * 2);  // only first 128 rows valid
    (void)ws_size;

    const int eb = (E + 255) / 256;
    const int nb = (N + 255) / 256;

    // ---- CSR build ----
    hipMemsetAsync(cnt, 0, (size_t)N * 4, stream);
    k_count<<<eb, 256, 0, stream>>>(dst, cnt, E);
    k_scan_block<<<nb, 256, 0, stream>>>(cnt, bsum, N);
    k_scan_top<<<1, 512, 0, stream>>>(bsum, nb);
    k_scan_down<<<nb, 256, 0, stream>>>(cnt, bsum, row_off, N, E);
    hipMemsetAsync(fill, 0, (size_t)N * 4, stream);
    k_scatter<<<eb, 256, 0, stream>>>(src, dst, row_off, fill, col, E);

    // ---- conversions ----
    k_f2b<<<(N * HID / 4 + 255) / 256, 256, 0, stream>>>(x, xb, N * HID / 4);
    k_wt_all<<<(2 * L + 1) * (HID * HID / 256), 256, 0, stream>>>(
        Ws, Wn, nd_W1, WsT, WnT, ndW1T, L);

    // ---- zero fused-dot accumulators ----
    hipMemsetAsync(sarr, 0, (size_t)N * 4, stream);
    hipMemsetAsync(out + G, 0, (size_t)N * 4, stream);

    // ---- GNN layers ----
    const int gx = (N + 127) / 128;
    const u16* hin = xb;
    u16* hout = hb1;
    for (int l = 0; l < L; ++l) {
        bool last = (l == L - 1);
        k_agg<<<(N + 3) / 4, 256, 0, stream>>>(hin, row_off, col, msgb, N);
        k_gemm_bf<<<gx, 512, 0, stream>>>(
            hin, WsT + (size_t)l * HID * HID, msgb, WnT + (size_t)l * HID * HID,
            bs + (size_t)l * HID, hout, N, HID,
            last ? att_w : nullptr, last ? att_b : nullptr, last ? sarr : nullptr);
        hin = hout;
        hout = (hout == hb1) ? hb2 : hb1;
    }
    const u16* h = hin;

    // ---- attention pooling (alpha fused into pool) ----
    k_gstart<<<nb, 256, 0, stream>>>(batch, gstart, N, G);
    k_mdenom<<<G, 256, 0, stream>>>(sarr, gstart, marr, denom);
    hipMemsetAsync(gpool, 0, (size_t)G * HID * 4, stream);
    k_pool<<<dim3(G, 16), HID, 0, stream>>>(h, sarr, marr, denom, gstart, gpool);

    // ---- graph head ----
    k_ghead<<<G, HHALF, 0, stream>>>(gpool, ne_W1, ne_b1, ne_W2, ne_b2, out);

    // ---- node head: dedicated 128-col fused GEMM+dot ----
    k_ndhead<<<gx, 256, 0, stream>>>(
        h, ndW1T, nd_b1, N, nd_W2, nd_b2, out + G);
}

// Round 15
// 533.135 us; speedup vs baseline: 1.1495x; 1.1495x over previous
//
#include <hip/hip_runtime.h>
#include <hip/hip_bf16.h>

#define HID 256
#define HHALF 128

typedef unsigned short u16;
typedef __attribute__((ext_vector_type(8))) short bf16x8;
typedef __attribute__((ext_vector_type(4))) float f32x4;

__device__ __forceinline__ float bf2f(unsigned int u) {
    unsigned int x = (u & 0xffffu) << 16;
    union { unsigned int i; float f; } c; c.i = x; return c.f;
}
__device__ __forceinline__ float lof(unsigned u) {
    union { unsigned i; float f; } c; c.i = u << 16; return c.f;
}
__device__ __forceinline__ float hif(unsigned u) {
    union { unsigned i; float f; } c; c.i = u & 0xffff0000u; return c.f;
}
__device__ __forceinline__ u16 f2bf(float f) {
    __hip_bfloat16 h = __float2bfloat16(f);   // RNE
    union { __hip_bfloat16 h; u16 u; } c; c.h = h; return c.u;
}

// async global->LDS, 16B per lane; lds dest is wave-uniform base + lane*16
__device__ __forceinline__ void gload16(const u16* g, u16* l) {
    __builtin_amdgcn_global_load_lds(
        (const __attribute__((address_space(1))) void*)g,
        (__attribute__((address_space(3))) void*)l, 16, 0, 0);
}

// lower_bound on sorted int array
__device__ __forceinline__ int lbound(const int* __restrict__ a, int n, int key) {
    int lo = 0, hi = n;
    while (lo < hi) {
        int mid = (lo + hi) >> 1;
        if (a[mid] < key) lo = mid + 1; else hi = mid;
    }
    return lo;
}

// ---------------- CSR build ----------------
__global__ void k_count(const int* __restrict__ dst, int* __restrict__ cnt, int E) {
    int i = blockIdx.x * blockDim.x + threadIdx.x;
    if (i < E) atomicAdd(&cnt[dst[i]], 1);
}

__global__ void k_scan_block(const int* __restrict__ cnt, int* __restrict__ bsum, int n) {
    __shared__ int sd[256];
    int tid = threadIdx.x;
    int i = blockIdx.x * 256 + tid;
    int v = (i < n) ? cnt[i] : 0;
    sd[tid] = v; __syncthreads();
    for (int s = 128; s > 0; s >>= 1) {
        if (tid < s) sd[tid] += sd[tid + s];
        __syncthreads();
    }
    if (tid == 0) bsum[blockIdx.x] = sd[0];
}

__global__ void k_scan_top(int* __restrict__ bsum, int nb) {
    __shared__ int sd[512];
    int t = threadIdx.x;
    int v = (t < nb) ? bsum[t] : 0;
    sd[t] = v; __syncthreads();
    for (int s = 1; s < 512; s <<= 1) {
        int x = (t >= s) ? sd[t - s] : 0;
        __syncthreads();
        sd[t] += x;
        __syncthreads();
    }
    if (t < nb) bsum[t] = sd[t] - v;  // exclusive
}

__global__ void k_scan_down(const int* __restrict__ cnt, const int* __restrict__ boff,
                            int* __restrict__ row_off, int n, int total) {
    __shared__ int sd[256];
    int tid = threadIdx.x;
    int i = blockIdx.x * 256 + tid;
    int v = (i < n) ? cnt[i] : 0;
    sd[tid] = v; __syncthreads();
    for (int s = 1; s < 256; s <<= 1) {
        int x = (tid >= s) ? sd[tid - s] : 0;
        __syncthreads();
        sd[tid] += x;
        __syncthreads();
    }
    if (i < n) row_off[i] = boff[blockIdx.x] + sd[tid] - v;
    if (i == 0) row_off[n] = total;
}

__global__ void k_scatter(const int* __restrict__ src, const int* __restrict__ dst,
                          const int* __restrict__ row_off, int* __restrict__ fill,
                          int* __restrict__ col, int E) {
    int i = blockIdx.x * blockDim.x + threadIdx.x;
    if (i < E) {
        int d = dst[i];
        int p = atomicAdd(&fill[d], 1);
        col[row_off[d] + p] = src[i];
    }
}

// ---------------- conversions ----------------
__global__ void k_f2b(const float* __restrict__ in, u16* __restrict__ o, int total4) {
    int i = blockIdx.x * blockDim.x + threadIdx.x;
    if (i >= total4) return;
    float4 v = *(const float4*)&in[(size_t)i * 4];
    uint2 p;
    p.x = (unsigned)f2bf(v.x) | ((unsigned)f2bf(v.y) << 16);
    p.y = (unsigned)f2bf(v.z) | ((unsigned)f2bf(v.w) << 16);
    *(uint2*)&o[(size_t)i * 4] = p;
}

// all weight transposes in one launch: mats 0..L-1 = Ws, L..2L-1 = Wn, 2L = nd_W1
__global__ void k_wt_all(const float* __restrict__ Ws, const float* __restrict__ Wn,
                         const float* __restrict__ ndW1,
                         u16* __restrict__ WsT, u16* __restrict__ WnT,
                         u16* __restrict__ ndW1T, int L) {
    int idx = blockIdx.x * 256 + threadIdx.x;
    int mat = idx >> 16;            // 65536 elems per 256x256 slot
    int r = idx & 65535;
    int k = r >> 8, c = r & 255;
    if (mat < L) {
        WsT[(size_t)mat * 65536 + c * 256 + k] = f2bf(Ws[(size_t)mat * 65536 + k * 256 + c]);
    } else if (mat < 2 * L) {
        int l = mat - L;
        WnT[(size_t)l * 65536 + c * 256 + k] = f2bf(Wn[(size_t)l * 65536 + k * 256 + c]);
    } else {
        if (c < HHALF) ndW1T[c * 256 + k] = f2bf(ndW1[k * HHALF + c]);
    }
}

// ---------------- mean aggregation (bf16 in/out, fp32 accum) ----------------
// 4 waves/block, one node per wave; halves take alternate neighbors; unroll x8
// main loop + single clamped-load masked tail (keeps 4 loads in flight).
__global__ __launch_bounds__(256) void k_agg(
    const u16* __restrict__ h, const int* __restrict__ row_off,
    const int* __restrict__ col, u16* __restrict__ msg, int n) {
    int node = blockIdx.x * 4 + (threadIdx.x >> 6);
    if (node >= n) return;
    int lane = threadIdx.x & 63;
    int half = lane >> 5;
    int t = lane & 31;              // owns channels t*8 .. t*8+7
    int s0 = row_off[node], s1 = row_off[node + 1];
    float a0 = 0.f, a1 = 0.f, a2 = 0.f, a3 = 0.f;
    float a4 = 0.f, a5 = 0.f, a6 = 0.f, a7 = 0.f;
    int e = s0;
    for (; e + 8 <= s1; e += 8) {
        int c0 = col[e + half];
        int c1 = col[e + 2 + half];
        int c2 = col[e + 4 + half];
        int c3 = col[e + 6 + half];
        uint4 v0 = *(const uint4*)&h[(size_t)c0 * HID + t * 8];
        uint4 v1 = *(const uint4*)&h[(size_t)c1 * HID + t * 8];
        uint4 v2 = *(const uint4*)&h[(size_t)c2 * HID + t * 8];
        uint4 v3 = *(const uint4*)&h[(size_t)c3 * HID + t * 8];
        a0 += (lof(v0.x) + lof(v1.x)) + (lof(v2.x) + lof(v3.x));
        a1 += (hif(v0.x) + hif(v1.x)) + (hif(v2.x) + hif(v3.x));
        a2 += (lof(v0.y) + lof(v1.y)) + (lof(v2.y) + lof(v3.y));
        a3 += (hif(v0.y) + hif(v1.y)) + (hif(v2.y) + hif(v3.y));
        a4 += (lof(v0.z) + lof(v1.z)) + (lof(v2.z) + lof(v3.z));
        a5 += (hif(v0.z) + hif(v1.z)) + (hif(v2.z) + hif(v3.z));
        a6 += (lof(v0.w) + lof(v1.w)) + (lof(v2.w) + lof(v3.w));
        a7 += (hif(v0.w) + hif(v1.w)) + (hif(v2.w) + hif(v3.w));
    }
    if (e < s1) {
        int i0 = e + half, i1 = e + 2 + half, i2 = e + 4 + half, i3 = e + 6 + half;
        float w0 = (i0 < s1) ? 1.f : 0.f; int c0 = col[(i0 < s1) ? i0 : s0];
        float w1 = (i1 < s1) ? 1.f : 0.f; int c1 = col[(i1 < s1) ? i1 : s0];
        float w2 = (i2 < s1) ? 1.f : 0.f; int c2 = col[(i2 < s1) ? i2 : s0];
        float w3 = (i3 < s1) ? 1.f : 0.f; int c3 = col[(i3 < s1) ? i3 : s0];
        uint4 v0 = *(const uint4*)&h[(size_t)c0 * HID + t * 8];
        uint4 v1 = *(const uint4*)&h[(size_t)c1 * HID + t * 8];
        uint4 v2 = *(const uint4*)&h[(size_t)c2 * HID + t * 8];
        uint4 v3 = *(const uint4*)&h[(size_t)c3 * HID + t * 8];
        a0 = fmaf(w0, lof(v0.x), fmaf(w1, lof(v1.x), fmaf(w2, lof(v2.x), fmaf(w3, lof(v3.x), a0))));
        a1 = fmaf(w0, hif(v0.x), fmaf(w1, hif(v1.x), fmaf(w2, hif(v2.x), fmaf(w3, hif(v3.x), a1))));
        a2 = fmaf(w0, lof(v0.y), fmaf(w1, lof(v1.y), fmaf(w2, lof(v2.y), fmaf(w3, lof(v3.y), a2))));
        a3 = fmaf(w0, hif(v0.y), fmaf(w1, hif(v1.y), fmaf(w2, hif(v2.y), fmaf(w3, hif(v3.y), a3))));
        a4 = fmaf(w0, lof(v0.z), fmaf(w1, lof(v1.z), fmaf(w2, lof(v2.z), fmaf(w3, lof(v3.z), a4))));
        a5 = fmaf(w0, hif(v0.z), fmaf(w1, hif(v1.z), fmaf(w2, hif(v2.z), fmaf(w3, hif(v3.z), a5))));
        a6 = fmaf(w0, lof(v0.w), fmaf(w1, lof(v1.w), fmaf(w2, lof(v2.w), fmaf(w3, lof(v3.w), a6))));
        a7 = fmaf(w0, hif(v0.w), fmaf(w1, hif(v1.w), fmaf(w2, hif(v2.w), fmaf(w3, hif(v3.w), a7))));
    }
    a0 += __shfl_xor(a0, 32); a1 += __shfl_xor(a1, 32);
    a2 += __shfl_xor(a2, 32); a3 += __shfl_xor(a3, 32);
    a4 += __shfl_xor(a4, 32); a5 += __shfl_xor(a5, 32);
    a6 += __shfl_xor(a6, 32); a7 += __shfl_xor(a7, 32);
    if (half == 0) {
        int deg = s1 - s0;
        float inv = 1.0f / (float)(deg > 1 ? deg : 1);
        uint4 o;
        o.x = (unsigned)f2bf(a0 * inv) | ((unsigned)f2bf(a1 * inv) << 16);
        o.y = (unsigned)f2bf(a2 * inv) | ((unsigned)f2bf(a3 * inv) << 16);
        o.z = (unsigned)f2bf(a4 * inv) | ((unsigned)f2bf(a5 * inv) << 16);
        o.w = (unsigned)f2bf(a6 * inv) | ((unsigned)f2bf(a7 * inv) << 16);
        *(uint4*)&msg[(size_t)node * HID + t * 8] = o;
    }
}

// ---------------- bf16 MFMA GEMM: out = relu(A1@W1 [+ A2@W2] + bias) ----------------
// R13-verified core: 128x256 tile, 8 waves (2x4), BK=64, single-buffer
// global_load_lds, 2-barrier loop, 3-bit XOR chunk swizzle both sides, swapped
// operands. Fused row-dot epilogue now uses LDS reduce (reusing As) + direct
// store — no atomics, no pre-zeroed buffer.
__global__ __launch_bounds__(512) void k_gemm_bf(
    const u16* __restrict__ A1, const u16* __restrict__ W1t,
    const u16* __restrict__ A2, const u16* __restrict__ W2t,
    const float* __restrict__ bias, u16* __restrict__ out,
    int n, int ncols,
    const float* __restrict__ dotw, const float* __restrict__ dotb,
    float* __restrict__ dotout) {
    __shared__ __align__(16) u16 As[128 * 64];   // 16 KB
    __shared__ __align__(16) u16 Bs[256 * 64];   // 32 KB
    const int tid  = threadIdx.x;
    const int lane = tid & 63;
    const int w    = tid >> 6;           // 0..7
    const int wr   = w >> 2, wc = w & 3; // wave tile: rows wr*64+, cols wc*64+
    const int brow = blockIdx.x * 128;
    const int nkt  = A2 ? 8 : 4;         // BK=64: 4 K-steps per operand phase

    f32x4 acc[4][4];
    #pragma unroll
    for (int m = 0; m < 4; ++m)
        #pragma unroll
        for (int q = 0; q < 4; ++q)
            acc[m][q] = (f32x4){0.f, 0.f, 0.f, 0.f};

    // staging: slot s -> tile row = s>>3, chunk = s&7 (16B chunks, 8 per row).
    // LDS deposit linear; source chunk pre-swizzled: (s&7) ^ ((row>>1)&7).
    const int as0 = tid, as1 = tid + 512;
    int ar0 = brow + (as0 >> 3); if (ar0 >= n) ar0 = n - 1;
    int ar1 = brow + (as1 >> 3); if (ar1 >= n) ar1 = n - 1;
    const size_t asrc0 = (size_t)ar0 * HID + (size_t)(((as0 & 7) ^ (((as0 >> 3) >> 1) & 7)) * 8);
    const size_t asrc1 = (size_t)ar1 * HID + (size_t)(((as1 & 7) ^ (((as1 >> 3) >> 1) & 7)) * 8);
    u16* adst0 = &As[(w * 64) * 8];            // wave-uniform; HW adds lane*16
    u16* adst1 = &As[(512 + w * 64) * 8];

    size_t bsrc[4];
    u16*   bdst[4];
    #pragma unroll
    for (int i = 0; i < 4; ++i) {
        int s = tid + i * 512;
        int row = s >> 3;                      // Wt row 0..255
        bsrc[i] = (size_t)row * HID + (size_t)(((s & 7) ^ ((row >> 1) & 7)) * 8);
        bdst[i] = &Bs[(i * 512 + w * 64) * 8];
    }

    const int lr = lane & 15;
    const int lq = lane >> 4;
    const int swz = (lr >> 1) & 7;             // row-swizzle bits for fragment reads

    for (int kt = 0; kt < nkt; ++kt) {
        const u16* A = (kt < 4) ? A1 : A2;
        const u16* W = (kt < 4) ? W1t : W2t;
        const int k0 = (kt & 3) * 64;
        __syncthreads();                  // all waves done reading previous tile
        gload16(A + asrc0 + k0, adst0);
        gload16(A + asrc1 + k0, adst1);
        gload16(W + bsrc[0] + k0, bdst[0]);
        gload16(W + bsrc[1] + k0, bdst[1]);
        gload16(W + bsrc[2] + k0, bdst[2]);
        gload16(W + bsrc[3] + k0, bdst[3]);
        __syncthreads();                  // vmcnt(0) drain -> tile staged
        #pragma unroll
        for (int ks = 0; ks < 2; ++ks) {
            const int ch = (ks * 4 + lq) ^ swz;
            bf16x8 af[4], bg[4];
            #pragma unroll
            for (int m = 0; m < 4; ++m)
                af[m] = *(const bf16x8*)&As[(wr * 64 + m * 16 + lr) * 64 + ch * 8];
            #pragma unroll
            for (int q = 0; q < 4; ++q)
                bg[q] = *(const bf16x8*)&Bs[(wc * 64 + q * 16 + lr) * 64 + ch * 8];
            #pragma unroll
            for (int m = 0; m < 4; ++m)
                #pragma unroll
                for (int q = 0; q < 4; ++q)
                    acc[m][q] = __builtin_amdgcn_mfma_f32_16x16x32_bf16(
                        bg[q], af[m], acc[m][q], 0, 0, 0);  // swapped: lane holds 4 cols of a row
        }
    }

    // epilogue: row = brow+wr*64+m*16+lr; col = wc*64+q*16+lq*4+j
    if (dotout) __syncthreads();          // about to reuse As as float[128][4]
    float* dred = (float*)As;
    #pragma unroll
    for (int m = 0; m < 4; ++m) {
        int row = brow + wr * 64 + m * 16 + lr;
        bool rok = row < n;
        float dpart = 0.f;
        #pragma unroll
        for (int q = 0; q < 4; ++q) {
            int col = wc * 64 + q * 16 + lq * 4;
            if (col < ncols) {
                float4 bb = *(const float4*)&bias[col];
                float r0 = fmaxf(acc[m][q][0] + bb.x, 0.f);
                float r1 = fmaxf(acc[m][q][1] + bb.y, 0.f);
                float r2 = fmaxf(acc[m][q][2] + bb.z, 0.f);
                float r3 = fmaxf(acc[m][q][3] + bb.w, 0.f);
                if (out && rok) {
                    uint2 o;
                    o.x = (unsigned)f2bf(r0) | ((unsigned)f2bf(r1) << 16);
                    o.y = (unsigned)f2bf(r2) | ((unsigned)f2bf(r3) << 16);
                    *(uint2*)&out[(size_t)row * ncols + col] = o;
                }
                if (dotout) {
                    float4 wv = *(const float4*)&dotw[col];
                    dpart += r0 * wv.x + r1 * wv.y + r2 * wv.z + r3 * wv.w;
                }
            }
        }
        if (dotout) {
            dpart += __shfl_xor(dpart, 16);
            dpart += __shfl_xor(dpart, 32);
            if (lane < 16) dred[(wr * 64 + m * 16 + lane) * 4 + wc] = dpart;
        }
    }
    if (dotout) {
        __syncthreads();
        if (tid < 128) {
            int row = brow + tid;
            if (row < n) {
                float s = (dred[tid * 4 + 0] + dred[tid * 4 + 1])
                        + (dred[tid * 4 + 2] + dred[tid * 4 + 3]);
                dotout[row] = s + dotb[0];
            }
        }
    }
}

// ---------------- node head: dotout[row] = relu(h@W1t+b1) . dotw + dotb ----------------
// R13-verified geometry (128x128, 4 waves, BK=64, nkt=4) with LDS-reduce dot
// (no atomics, no pre-zeroed output).
__global__ __launch_bounds__(256) void k_ndhead(
    const u16* __restrict__ A1, const u16* __restrict__ W1t,
    const float* __restrict__ bias, int n,
    const float* __restrict__ dotw, const float* __restrict__ dotb,
    float* __restrict__ dotout) {
    __shared__ __align__(16) u16 As[128 * 64];   // 16 KB
    __shared__ __align__(16) u16 Bs[128 * 64];   // 16 KB
    const int tid  = threadIdx.x;
    const int lane = tid & 63;
    const int w    = tid >> 6;           // 0..3
    const int wr   = w >> 1, wc = w & 1;
    const int brow = blockIdx.x * 128;

    f32x4 acc[4][4];
    #pragma unroll
    for (int m = 0; m < 4; ++m)
        #pragma unroll
        for (int q = 0; q < 4; ++q)
            acc[m][q] = (f32x4){0.f, 0.f, 0.f, 0.f};

    size_t asrc[4], bsrc[4];
    u16 *adst[4], *bdst[4];
    #pragma unroll
    for (int i = 0; i < 4; ++i) {
        int s = tid + i * 256;           // chunk 0..1023
        int row = s >> 3;
        int ch = ((s & 7) ^ ((row >> 1) & 7)) * 8;
        int ar = brow + row; if (ar >= n) ar = n - 1;
        asrc[i] = (size_t)ar * HID + ch;
        bsrc[i] = (size_t)row * HID + ch;            // W1t rows 0..127 (stride 256)
        adst[i] = &As[(i * 256 + w * 64) * 8];       // wave-uniform
        bdst[i] = &Bs[(i * 256 + w * 64) * 8];
    }

    const int lr = lane & 15;
    const int lq = lane >> 4;
    const int swz = (lr >> 1) & 7;

    for (int kt = 0; kt < 4; ++kt) {
        const int k0 = kt * 64;
        __syncthreads();
        #pragma unroll
        for (int i = 0; i < 4; ++i) gload16(A1 + asrc[i] + k0, adst[i]);
        #pragma unroll
        for (int i = 0; i < 4; ++i) gload16(W1t + bsrc[i] + k0, bdst[i]);
        __syncthreads();
        #pragma unroll
        for (int ks = 0; ks < 2; ++ks) {
            const int ch = (ks * 4 + lq) ^ swz;
            bf16x8 af[4], bg[4];
            #pragma unroll
            for (int m = 0; m < 4; ++m)
                af[m] = *(const bf16x8*)&As[(wr * 64 + m * 16 + lr) * 64 + ch * 8];
            #pragma unroll
            for (int q = 0; q < 4; ++q)
                bg[q] = *(const bf16x8*)&Bs[(wc * 64 + q * 16 + lr) * 64 + ch * 8];
            #pragma unroll
            for (int m = 0; m < 4; ++m)
                #pragma unroll
                for (int q = 0; q < 4; ++q)
                    acc[m][q] = __builtin_amdgcn_mfma_f32_16x16x32_bf16(
                        bg[q], af[m], acc[m][q], 0, 0, 0);
        }
    }

    __syncthreads();                      // reuse As as float[128][2]
    float* dred = (float*)As;
    #pragma unroll
    for (int m = 0; m < 4; ++m) {
        float dpart = 0.f;
        #pragma unroll
        for (int q = 0; q < 4; ++q) {
            int col = wc * 64 + q * 16 + lq * 4;
            float4 bb = *(const float4*)&bias[col];
            float4 wv = *(const float4*)&dotw[col];
            dpart += fmaxf(acc[m][q][0] + bb.x, 0.f) * wv.x
                   + fmaxf(acc[m][q][1] + bb.y, 0.f) * wv.y
                   + fmaxf(acc[m][q][2] + bb.z, 0.f) * wv.z
                   + fmaxf(acc[m][q][3] + bb.w, 0.f) * wv.w;
        }
        dpart += __shfl_xor(dpart, 16);
        dpart += __shfl_xor(dpart, 32);
        if (lane < 16) dred[(wr * 64 + m * 16 + lane) * 2 + wc] = dpart;
    }
    __syncthreads();
    if (tid < 128) {
        int row = brow + tid;
        if (row < n) dotout[row] = dred[tid * 2 + 0] + dred[tid * 2 + 1] + dotb[0];
    }
}

// ---------------- per-graph max + softmax denom (bounds via binary search) ----------------
__global__ void k_mdenom(const float* __restrict__ s, const int* __restrict__ batch,
                         int n, float* __restrict__ m, float* __restrict__ denom) {
    int g = blockIdx.x;
    int t = threadIdx.x;
    int i0 = lbound(batch, n, g);
    int i1 = lbound(batch, n, g + 1);
    __shared__ float red[256];
    float mx = -INFINITY;
    for (int i = i0 + t; i < i1; i += 256) mx = fmaxf(mx, s[i]);
    red[t] = mx; __syncthreads();
    for (int st = 128; st; st >>= 1) {
        if (t < st) red[t] = fmaxf(red[t], red[t + st]);
        __syncthreads();
    }
    float gm = red[0];
    __syncthreads();
    float sm = 0.f;
    for (int i = i0 + t; i < i1; i += 256) sm += expf(s[i] - gm);
    red[t] = sm; __syncthreads();
    for (int st = 128; st; st >>= 1) {
        if (t < st) red[t] += red[t + st];
        __syncthreads();
    }
    if (t == 0) { m[g] = gm; denom[g] = red[0]; }
}

// ---------------- attention pooling: per-(g,sp) partial, no atomics ----------------
__global__ void k_pool(const u16* __restrict__ h, const float* __restrict__ sarr,
                       const float* __restrict__ marr, const float* __restrict__ denom,
                       const int* __restrict__ batch, int n, int G,
                       float* __restrict__ gpool16) {
    int g = blockIdx.x, sp = blockIdx.y, t = threadIdx.x;
    int i0 = lbound(batch, n, g);
    int i1 = lbound(batch, n, g + 1);
    int len = i1 - i0;
    int a = i0 + (int)((long long)len * sp / 16);
    int b = i0 + (int)((long long)len * (sp + 1) / 16);
    float dn = denom[g];
    float inv = (dn > 0.f) ? 1.0f / dn : 0.f;
    float mg = marr[g];
    float acc = 0.f;
    for (int i = a; i < b; ++i)
        acc += expf(sarr[i] - mg) * inv * bf2f(h[(size_t)i * HID + t]);
    gpool16[((size_t)sp * G + g) * HID + t] = acc;
}

// ---------------- graph head (sums the 16 pool partials on load) ----------------
__global__ void k_ghead(const float* __restrict__ gpool16, int G,
                        const float* __restrict__ W1, const float* __restrict__ b1,
                        const float* __restrict__ W2, const float* __restrict__ b2,
                        float* __restrict__ out) {
    int g = blockIdx.x, t = threadIdx.x;  // 128 threads
    __shared__ float row[HID];
    __shared__ float red[128];
    float v0 = 0.f, v1 = 0.f;
    for (int sp = 0; sp < 16; ++sp) {
        const float* p = gpool16 + ((size_t)sp * G + g) * HID;
        v0 += p[t];
        v1 += p[t + 128];
    }
    row[t] = v0;
    row[t + 128] = v1;
    __syncthreads();
    float acc = 0.f;
    #pragma unroll 8
    for (int k = 0; k < HID; ++k) acc = fmaf(row[k], W1[k * HHALF + t], acc);
    float hid = fmaxf(acc + b1[t], 0.f);
    red[t] = hid * W2[t];
    __syncthreads();
    for (int st = 64; st; st >>= 1) {
        if (t < st) red[t] += red[t + st];
        __syncthreads();
    }
    if (t == 0) out[g] = red[0] + b2[0];
}

extern "C" void kernel_launch(void* const* d_in, const int* in_sizes, int n_in,
                              void* d_out, int out_size, void* d_ws, size_t ws_size,
                              hipStream_t stream) {
    const float* x      = (const float*)d_in[0];
    const int*   eidx   = (const int*)d_in[1];
    const int*   batch  = (const int*)d_in[2];
    const float* Ws     = (const float*)d_in[3];
    const float* Wn     = (const float*)d_in[4];
    const float* bs     = (const float*)d_in[5];
    const float* att_w  = (const float*)d_in[6];
    const float* att_b  = (const float*)d_in[7];
    const float* ne_W1  = (const float*)d_in[8];
    const float* ne_b1  = (const float*)d_in[9];
    const float* ne_W2  = (const float*)d_in[10];
    const float* ne_b2  = (const float*)d_in[11];
    const float* nd_W1  = (const float*)d_in[12];
    const float* nd_b1  = (const float*)d_in[13];
    const float* nd_W2  = (const float*)d_in[14];
    const float* nd_b2  = (const float*)d_in[15];
    float* out = (float*)d_out;

    const int N = in_sizes[2];
    const int E = in_sizes[1] / 2;
    const int L = in_sizes[3] / (HID * HID);
    const int G = out_size - N;

    const int* src = eidx;
    const int* dst = eidx + E;

    size_t off = 0;
    auto alloc = [&](size_t bytes) {
        void* p = (char*)d_ws + off;
        off += (bytes + 255) & ~(size_t)255;
        return p;
    };
    int*   cnt     = (int*)alloc((size_t)N * 4);
    int*   row_off = (int*)alloc((size_t)(N + 1) * 4);
    int*   fill    = (int*)alloc((size_t)N * 4);
    int*   col     = (int*)alloc((size_t)E * 4);
    int*   bsum    = (int*)alloc(1024 * 4);
    float* sarr    = (float*)alloc((size_t)N * 4);
    float* marr    = (float*)alloc((size_t)G * 4);
    float* denom   = (float*)alloc((size_t)G * 4);
    float* gpool16 = (float*)alloc((size_t)16 * G * HID * 4);
    u16*   xb      = (u16*)alloc((size_t)N * HID * 2);
    u16*   msgb    = (u16*)alloc((size_t)N * HID * 2);
    u16*   hb1     = (u16*)alloc((size_t)N * HID * 2);
    u16*   hb2     = (u16*)alloc((size_t)N * HID * 2);
    u16*   WsT     = (u16*)alloc((size_t)L * HID * HID * 2);
    u16*   WnT     = (u16*)alloc((size_t)L * HID * HID * 2);
    u16*   ndW1T   = (u16*)alloc((size_t)HID * HID * 2);  // only first 128 rows valid
    (void)ws_size;

    const int eb = (E + 255) / 256;
    const int nb = (N + 255) / 256;

    // ---- CSR build ----
    hipMemsetAsync(cnt, 0, (size_t)N * 4, stream);
    k_count<<<eb, 256, 0, stream>>>(dst, cnt, E);
    k_scan_block<<<nb, 256, 0, stream>>>(cnt, bsum, N);
    k_scan_top<<<1, 512, 0, stream>>>(bsum, nb);
    k_scan_down<<<nb, 256, 0, stream>>>(cnt, bsum, row_off, N, E);
    hipMemsetAsync(fill, 0, (size_t)N * 4, stream);
    k_scatter<<<eb, 256, 0, stream>>>(src, dst, row_off, fill, col, E);

    // ---- conversions ----
    k_f2b<<<(N * HID / 4 + 255) / 256, 256, 0, stream>>>(x, xb, N * HID / 4);
    k_wt_all<<<(2 * L + 1) * (HID * HID / 256), 256, 0, stream>>>(
        Ws, Wn, nd_W1, WsT, WnT, ndW1T, L);

    // ---- GNN layers ----
    const int gx = (N + 127) / 128;
    const u16* hin = xb;
    u16* hout = hb1;
    for (int l = 0; l < L; ++l) {
        bool last = (l == L - 1);
        k_agg<<<(N + 3) / 4, 256, 0, stream>>>(hin, row_off, col, msgb, N);
        k_gemm_bf<<<gx, 512, 0, stream>>>(
            hin, WsT + (size_t)l * HID * HID, msgb, WnT + (size_t)l * HID * HID,
            bs + (size_t)l * HID, hout, N, HID,
            last ? att_w : nullptr, last ? att_b : nullptr, last ? sarr : nullptr);
        hin = hout;
        hout = (hout == hb1) ? hb2 : hb1;
    }
    const u16* h = hin;

    // ---- attention pooling ----
    k_mdenom<<<G, 256, 0, stream>>>(sarr, batch, N, marr, denom);
    k_pool<<<dim3(G, 16), HID, 0, stream>>>(h, sarr, marr, denom, batch, N, G, gpool16);

    // ---- graph head ----
    k_ghead<<<G, HHALF, 0, stream>>>(gpool16, G, ne_W1, ne_b1, ne_W2, ne_b2, out);

    // ---- node head: dedicated 128-col fused GEMM+dot (direct store) ----
    k_ndhead<<<gx, 256, 0, stream>>>(
        h, ndW1T, nd_b1, N, nd_W2, nd_b2, out + G);
}

// Round 16
// 531.113 us; speedup vs baseline: 1.1539x; 1.0038x over previous
//
#include <hip/hip_runtime.h>
#include <hip/hip_bf16.h>

#define HID 256
#define HHALF 128

typedef unsigned short u16;
typedef __attribute__((ext_vector_type(8))) short bf16x8;
typedef __attribute__((ext_vector_type(4))) float f32x4;

__device__ __forceinline__ float bf2f(unsigned int u) {
    unsigned int x = (u & 0xffffu) << 16;
    union { unsigned int i; float f; } c; c.i = x; return c.f;
}
__device__ __forceinline__ float lof(unsigned u) {
    union { unsigned i; float f; } c; c.i = u << 16; return c.f;
}
__device__ __forceinline__ float hif(unsigned u) {
    union { unsigned i; float f; } c; c.i = u & 0xffff0000u; return c.f;
}
__device__ __forceinline__ u16 f2bf(float f) {
    __hip_bfloat16 h = __float2bfloat16(f);   // RNE
    union { __hip_bfloat16 h; u16 u; } c; c.h = h; return c.u;
}

// async global->LDS, 16B per lane; lds dest is wave-uniform base + lane*16
__device__ __forceinline__ void gload16(const u16* g, u16* l) {
    __builtin_amdgcn_global_load_lds(
        (const __attribute__((address_space(1))) void*)g,
        (__attribute__((address_space(3))) void*)l, 16, 0, 0);
}

// lower_bound on sorted int array
__device__ __forceinline__ int lbound(const int* __restrict__ a, int n, int key) {
    int lo = 0, hi = n;
    while (lo < hi) {
        int mid = (lo + hi) >> 1;
        if (a[mid] < key) lo = mid + 1; else hi = mid;
    }
    return lo;
}

// ---------------- CSR build ----------------
__global__ void k_count(const int* __restrict__ dst, int* __restrict__ cnt, int E) {
    int i = blockIdx.x * blockDim.x + threadIdx.x;
    if (i < E) atomicAdd(&cnt[dst[i]], 1);
}

__global__ void k_scan_block(const int* __restrict__ cnt, int* __restrict__ bsum, int n) {
    __shared__ int sd[256];
    int tid = threadIdx.x;
    int i = blockIdx.x * 256 + tid;
    int v = (i < n) ? cnt[i] : 0;
    sd[tid] = v; __syncthreads();
    for (int s = 128; s > 0; s >>= 1) {
        if (tid < s) sd[tid] += sd[tid + s];
        __syncthreads();
    }
    if (tid == 0) bsum[blockIdx.x] = sd[0];
}

__global__ void k_scan_top(int* __restrict__ bsum, int nb) {
    __shared__ int sd[512];
    int t = threadIdx.x;
    int v = (t < nb) ? bsum[t] : 0;
    sd[t] = v; __syncthreads();
    for (int s = 1; s < 512; s <<= 1) {
        int x = (t >= s) ? sd[t - s] : 0;
        __syncthreads();
        sd[t] += x;
        __syncthreads();
    }
    if (t < nb) bsum[t] = sd[t] - v;  // exclusive
}

__global__ void k_scan_down(const int* __restrict__ cnt, const int* __restrict__ boff,
                            int* __restrict__ row_off, int n, int total) {
    __shared__ int sd[256];
    int tid = threadIdx.x;
    int i = blockIdx.x * 256 + tid;
    int v = (i < n) ? cnt[i] : 0;
    sd[tid] = v; __syncthreads();
    for (int s = 1; s < 256; s <<= 1) {
        int x = (tid >= s) ? sd[tid - s] : 0;
        __syncthreads();
        sd[tid] += x;
        __syncthreads();
    }
    if (i < n) row_off[i] = boff[blockIdx.x] + sd[tid] - v;
    if (i == 0) row_off[n] = total;
}

// claims slots by decrementing cnt (still holds degrees post-scan); no fill buffer
__global__ void k_scatter(const int* __restrict__ src, const int* __restrict__ dst,
                          const int* __restrict__ row_off, int* __restrict__ cnt,
                          int* __restrict__ col, int E) {
    int i = blockIdx.x * blockDim.x + threadIdx.x;
    if (i < E) {
        int d = dst[i];
        int p = atomicSub(&cnt[d], 1) - 1;
        col[row_off[d] + p] = src[i];
    }
}

// ---------------- prep: x -> bf16 AND weight transposes, one launch ----------------
// blocks [0, xb4/256): convert x (4 floats/thread)
// blocks beyond: transpose mats 0..L-1 = Ws, L..2L-1 = Wn, 2L = nd_W1
__global__ void k_prep(const float* __restrict__ x, u16* __restrict__ xb, int xtotal4,
                       const float* __restrict__ Ws, const float* __restrict__ Wn,
                       const float* __restrict__ ndW1,
                       u16* __restrict__ WsT, u16* __restrict__ WnT,
                       u16* __restrict__ ndW1T, int L) {
    int idx = blockIdx.x * 256 + threadIdx.x;
    if (idx < xtotal4) {
        float4 v = *(const float4*)&x[(size_t)idx * 4];
        uint2 p;
        p.x = (unsigned)f2bf(v.x) | ((unsigned)f2bf(v.y) << 16);
        p.y = (unsigned)f2bf(v.z) | ((unsigned)f2bf(v.w) << 16);
        *(uint2*)&xb[(size_t)idx * 4] = p;
        return;
    }
    int widx = idx - xtotal4;
    int mat = widx >> 16;            // 65536 elems per 256x256 slot
    if (mat >= 2 * L + 1) return;
    int r = widx & 65535;
    int k = r >> 8, c = r & 255;
    if (mat < L) {
        WsT[(size_t)mat * 65536 + c * 256 + k] = f2bf(Ws[(size_t)mat * 65536 + k * 256 + c]);
    } else if (mat < 2 * L) {
        int l = mat - L;
        WnT[(size_t)l * 65536 + c * 256 + k] = f2bf(Wn[(size_t)l * 65536 + k * 256 + c]);
    } else {
        if (c < HHALF) ndW1T[c * 256 + k] = f2bf(ndW1[k * HHALF + c]);
    }
}

// ---------------- mean aggregation (bf16 in/out, fp32 accum) ----------------
// 4 waves/block, one node per wave; halves take alternate neighbors; unroll x8
// main loop + single clamped-load masked tail (keeps 4 loads in flight).
__global__ __launch_bounds__(256) void k_agg(
    const u16* __restrict__ h, const int* __restrict__ row_off,
    const int* __restrict__ col, u16* __restrict__ msg, int n) {
    int node = blockIdx.x * 4 + (threadIdx.x >> 6);
    if (node >= n) return;
    int lane = threadIdx.x & 63;
    int half = lane >> 5;
    int t = lane & 31;              // owns channels t*8 .. t*8+7
    int s0 = row_off[node], s1 = row_off[node + 1];
    float a0 = 0.f, a1 = 0.f, a2 = 0.f, a3 = 0.f;
    float a4 = 0.f, a5 = 0.f, a6 = 0.f, a7 = 0.f;
    int e = s0;
    for (; e + 8 <= s1; e += 8) {
        int c0 = col[e + half];
        int c1 = col[e + 2 + half];
        int c2 = col[e + 4 + half];
        int c3 = col[e + 6 + half];
        uint4 v0 = *(const uint4*)&h[(size_t)c0 * HID + t * 8];
        uint4 v1 = *(const uint4*)&h[(size_t)c1 * HID + t * 8];
        uint4 v2 = *(const uint4*)&h[(size_t)c2 * HID + t * 8];
        uint4 v3 = *(const uint4*)&h[(size_t)c3 * HID + t * 8];
        a0 += (lof(v0.x) + lof(v1.x)) + (lof(v2.x) + lof(v3.x));
        a1 += (hif(v0.x) + hif(v1.x)) + (hif(v2.x) + hif(v3.x));
        a2 += (lof(v0.y) + lof(v1.y)) + (lof(v2.y) + lof(v3.y));
        a3 += (hif(v0.y) + hif(v1.y)) + (hif(v2.y) + hif(v3.y));
        a4 += (lof(v0.z) + lof(v1.z)) + (lof(v2.z) + lof(v3.z));
        a5 += (hif(v0.z) + hif(v1.z)) + (hif(v2.z) + hif(v3.z));
        a6 += (lof(v0.w) + lof(v1.w)) + (lof(v2.w) + lof(v3.w));
        a7 += (hif(v0.w) + hif(v1.w)) + (hif(v2.w) + hif(v3.w));
    }
    if (e < s1) {
        int i0 = e + half, i1 = e + 2 + half, i2 = e + 4 + half, i3 = e + 6 + half;
        float w0 = (i0 < s1) ? 1.f : 0.f; int c0 = col[(i0 < s1) ? i0 : s0];
        float w1 = (i1 < s1) ? 1.f : 0.f; int c1 = col[(i1 < s1) ? i1 : s0];
        float w2 = (i2 < s1) ? 1.f : 0.f; int c2 = col[(i2 < s1) ? i2 : s0];
        float w3 = (i3 < s1) ? 1.f : 0.f; int c3 = col[(i3 < s1) ? i3 : s0];
        uint4 v0 = *(const uint4*)&h[(size_t)c0 * HID + t * 8];
        uint4 v1 = *(const uint4*)&h[(size_t)c1 * HID + t * 8];
        uint4 v2 = *(const uint4*)&h[(size_t)c2 * HID + t * 8];
        uint4 v3 = *(const uint4*)&h[(size_t)c3 * HID + t * 8];
        a0 = fmaf(w0, lof(v0.x), fmaf(w1, lof(v1.x), fmaf(w2, lof(v2.x), fmaf(w3, lof(v3.x), a0))));
        a1 = fmaf(w0, hif(v0.x), fmaf(w1, hif(v1.x), fmaf(w2, hif(v2.x), fmaf(w3, hif(v3.x), a1))));
        a2 = fmaf(w0, lof(v0.y), fmaf(w1, lof(v1.y), fmaf(w2, lof(v2.y), fmaf(w3, lof(v3.y), a2))));
        a3 = fmaf(w0, hif(v0.y), fmaf(w1, hif(v1.y), fmaf(w2, hif(v2.y), fmaf(w3, hif(v3.y), a3))));
        a4 = fmaf(w0, lof(v0.z), fmaf(w1, lof(v1.z), fmaf(w2, lof(v2.z), fmaf(w3, lof(v3.z), a4))));
        a5 = fmaf(w0, hif(v0.z), fmaf(w1, hif(v1.z), fmaf(w2, hif(v2.z), fmaf(w3, hif(v3.z), a5))));
        a6 = fmaf(w0, lof(v0.w), fmaf(w1, lof(v1.w), fmaf(w2, lof(v2.w), fmaf(w3, lof(v3.w), a6))));
        a7 = fmaf(w0, hif(v0.w), fmaf(w1, hif(v1.w), fmaf(w2, hif(v2.w), fmaf(w3, hif(v3.w), a7))));
    }
    a0 += __shfl_xor(a0, 32); a1 += __shfl_xor(a1, 32);
    a2 += __shfl_xor(a2, 32); a3 += __shfl_xor(a3, 32);
    a4 += __shfl_xor(a4, 32); a5 += __shfl_xor(a5, 32);
    a6 += __shfl_xor(a6, 32); a7 += __shfl_xor(a7, 32);
    if (half == 0) {
        int deg = s1 - s0;
        float inv = 1.0f / (float)(deg > 1 ? deg : 1);
        uint4 o;
        o.x = (unsigned)f2bf(a0 * inv) | ((unsigned)f2bf(a1 * inv) << 16);
        o.y = (unsigned)f2bf(a2 * inv) | ((unsigned)f2bf(a3 * inv) << 16);
        o.z = (unsigned)f2bf(a4 * inv) | ((unsigned)f2bf(a5 * inv) << 16);
        o.w = (unsigned)f2bf(a6 * inv) | ((unsigned)f2bf(a7 * inv) << 16);
        *(uint4*)&msg[(size_t)node * HID + t * 8] = o;
    }
}

// ---------------- bf16 MFMA GEMM: out = relu(A1@W1 [+ A2@W2] + bias) ----------------
// R13/R15-verified core: 128x256 tile, 8 waves (2x4), BK=64, single-buffer
// global_load_lds, 2-barrier loop, 3-bit XOR chunk swizzle both sides, swapped
// operands. Fused row-dot epilogue via LDS reduce + direct store.
__global__ __launch_bounds__(512) void k_gemm_bf(
    const u16* __restrict__ A1, const u16* __restrict__ W1t,
    const u16* __restrict__ A2, const u16* __restrict__ W2t,
    const float* __restrict__ bias, u16* __restrict__ out,
    int n, int ncols,
    const float* __restrict__ dotw, const float* __restrict__ dotb,
    float* __restrict__ dotout) {
    __shared__ __align__(16) u16 As[128 * 64];   // 16 KB
    __shared__ __align__(16) u16 Bs[256 * 64];   // 32 KB
    const int tid  = threadIdx.x;
    const int lane = tid & 63;
    const int w    = tid >> 6;           // 0..7
    const int wr   = w >> 2, wc = w & 3; // wave tile: rows wr*64+, cols wc*64+
    const int brow = blockIdx.x * 128;
    const int nkt  = A2 ? 8 : 4;         // BK=64: 4 K-steps per operand phase

    f32x4 acc[4][4];
    #pragma unroll
    for (int m = 0; m < 4; ++m)
        #pragma unroll
        for (int q = 0; q < 4; ++q)
            acc[m][q] = (f32x4){0.f, 0.f, 0.f, 0.f};

    // staging: slot s -> tile row = s>>3, chunk = s&7 (16B chunks, 8 per row).
    // LDS deposit linear; source chunk pre-swizzled: (s&7) ^ ((row>>1)&7).
    const int as0 = tid, as1 = tid + 512;
    int ar0 = brow + (as0 >> 3); if (ar0 >= n) ar0 = n - 1;
    int ar1 = brow + (as1 >> 3); if (ar1 >= n) ar1 = n - 1;
    const size_t asrc0 = (size_t)ar0 * HID + (size_t)(((as0 & 7) ^ (((as0 >> 3) >> 1) & 7)) * 8);
    const size_t asrc1 = (size_t)ar1 * HID + (size_t)(((as1 & 7) ^ (((as1 >> 3) >> 1) & 7)) * 8);
    u16* adst0 = &As[(w * 64) * 8];            // wave-uniform; HW adds lane*16
    u16* adst1 = &As[(512 + w * 64) * 8];

    size_t bsrc[4];
    u16*   bdst[4];
    #pragma unroll
    for (int i = 0; i < 4; ++i) {
        int s = tid + i * 512;
        int row = s >> 3;                      // Wt row 0..255
        bsrc[i] = (size_t)row * HID + (size_t)(((s & 7) ^ ((row >> 1) & 7)) * 8);
        bdst[i] = &Bs[(i * 512 + w * 64) * 8];
    }

    const int lr = lane & 15;
    const int lq = lane >> 4;
    const int swz = (lr >> 1) & 7;             // row-swizzle bits for fragment reads

    for (int kt = 0; kt < nkt; ++kt) {
        const u16* A = (kt < 4) ? A1 : A2;
        const u16* W = (kt < 4) ? W1t : W2t;
        const int k0 = (kt & 3) * 64;
        __syncthreads();                  // all waves done reading previous tile
        gload16(A + asrc0 + k0, adst0);
        gload16(A + asrc1 + k0, adst1);
        gload16(W + bsrc[0] + k0, bdst[0]);
        gload16(W + bsrc[1] + k0, bdst[1]);
        gload16(W + bsrc[2] + k0, bdst[2]);
        gload16(W + bsrc[3] + k0, bdst[3]);
        __syncthreads();                  // vmcnt(0) drain -> tile staged
        #pragma unroll
        for (int ks = 0; ks < 2; ++ks) {
            const int ch = (ks * 4 + lq) ^ swz;
            bf16x8 af[4], bg[4];
            #pragma unroll
            for (int m = 0; m < 4; ++m)
                af[m] = *(const bf16x8*)&As[(wr * 64 + m * 16 + lr) * 64 + ch * 8];
            #pragma unroll
            for (int q = 0; q < 4; ++q)
                bg[q] = *(const bf16x8*)&Bs[(wc * 64 + q * 16 + lr) * 64 + ch * 8];
            #pragma unroll
            for (int m = 0; m < 4; ++m)
                #pragma unroll
                for (int q = 0; q < 4; ++q)
                    acc[m][q] = __builtin_amdgcn_mfma_f32_16x16x32_bf16(
                        bg[q], af[m], acc[m][q], 0, 0, 0);  // swapped: lane holds 4 cols of a row
        }
    }

    // epilogue: row = brow+wr*64+m*16+lr; col = wc*64+q*16+lq*4+j
    if (dotout) __syncthreads();          // about to reuse As as float[128][4]
    float* dred = (float*)As;
    #pragma unroll
    for (int m = 0; m < 4; ++m) {
        int row = brow + wr * 64 + m * 16 + lr;
        bool rok = row < n;
        float dpart = 0.f;
        #pragma unroll
        for (int q = 0; q < 4; ++q) {
            int col = wc * 64 + q * 16 + lq * 4;
            if (col < ncols) {
                float4 bb = *(const float4*)&bias[col];
                float r0 = fmaxf(acc[m][q][0] + bb.x, 0.f);
                float r1 = fmaxf(acc[m][q][1] + bb.y, 0.f);
                float r2 = fmaxf(acc[m][q][2] + bb.z, 0.f);
                float r3 = fmaxf(acc[m][q][3] + bb.w, 0.f);
                if (out && rok) {
                    uint2 o;
                    o.x = (unsigned)f2bf(r0) | ((unsigned)f2bf(r1) << 16);
                    o.y = (unsigned)f2bf(r2) | ((unsigned)f2bf(r3) << 16);
                    *(uint2*)&out[(size_t)row * ncols + col] = o;
                }
                if (dotout) {
                    float4 wv = *(const float4*)&dotw[col];
                    dpart += r0 * wv.x + r1 * wv.y + r2 * wv.z + r3 * wv.w;
                }
            }
        }
        if (dotout) {
            dpart += __shfl_xor(dpart, 16);
            dpart += __shfl_xor(dpart, 32);
            if (lane < 16) dred[(wr * 64 + m * 16 + lane) * 4 + wc] = dpart;
        }
    }
    if (dotout) {
        __syncthreads();
        if (tid < 128) {
            int row = brow + tid;
            if (row < n) {
                float s = (dred[tid * 4 + 0] + dred[tid * 4 + 1])
                        + (dred[tid * 4 + 2] + dred[tid * 4 + 3]);
                dotout[row] = s + dotb[0];
            }
        }
    }
}

// ---------------- node head: dotout[row] = relu(h@W1t+b1) . dotw + dotb ----------------
__global__ __launch_bounds__(256) void k_ndhead(
    const u16* __restrict__ A1, const u16* __restrict__ W1t,
    const float* __restrict__ bias, int n,
    const float* __restrict__ dotw, const float* __restrict__ dotb,
    float* __restrict__ dotout) {
    __shared__ __align__(16) u16 As[128 * 64];   // 16 KB
    __shared__ __align__(16) u16 Bs[128 * 64];   // 16 KB
    const int tid  = threadIdx.x;
    const int lane = tid & 63;
    const int w    = tid >> 6;           // 0..3
    const int wr   = w >> 1, wc = w & 1;
    const int brow = blockIdx.x * 128;

    f32x4 acc[4][4];
    #pragma unroll
    for (int m = 0; m < 4; ++m)
        #pragma unroll
        for (int q = 0; q < 4; ++q)
            acc[m][q] = (f32x4){0.f, 0.f, 0.f, 0.f};

    size_t asrc[4], bsrc[4];
    u16 *adst[4], *bdst[4];
    #pragma unroll
    for (int i = 0; i < 4; ++i) {
        int s = tid + i * 256;           // chunk 0..1023
        int row = s >> 3;
        int ch = ((s & 7) ^ ((row >> 1) & 7)) * 8;
        int ar = brow + row; if (ar >= n) ar = n - 1;
        asrc[i] = (size_t)ar * HID + ch;
        bsrc[i] = (size_t)row * HID + ch;            // W1t rows 0..127 (stride 256)
        adst[i] = &As[(i * 256 + w * 64) * 8];       // wave-uniform
        bdst[i] = &Bs[(i * 256 + w * 64) * 8];
    }

    const int lr = lane & 15;
    const int lq = lane >> 4;
    const int swz = (lr >> 1) & 7;

    for (int kt = 0; kt < 4; ++kt) {
        const int k0 = kt * 64;
        __syncthreads();
        #pragma unroll
        for (int i = 0; i < 4; ++i) gload16(A1 + asrc[i] + k0, adst[i]);
        #pragma unroll
        for (int i = 0; i < 4; ++i) gload16(W1t + bsrc[i] + k0, bdst[i]);
        __syncthreads();
        #pragma unroll
        for (int ks = 0; ks < 2; ++ks) {
            const int ch = (ks * 4 + lq) ^ swz;
            bf16x8 af[4], bg[4];
            #pragma unroll
            for (int m = 0; m < 4; ++m)
                af[m] = *(const bf16x8*)&As[(wr * 64 + m * 16 + lr) * 64 + ch * 8];
            #pragma unroll
            for (int q = 0; q < 4; ++q)
                bg[q] = *(const bf16x8*)&Bs[(wc * 64 + q * 16 + lr) * 64 + ch * 8];
            #pragma unroll
            for (int m = 0; m < 4; ++m)
                #pragma unroll
                for (int q = 0; q < 4; ++q)
                    acc[m][q] = __builtin_amdgcn_mfma_f32_16x16x32_bf16(
                        bg[q], af[m], acc[m][q], 0, 0, 0);
        }
    }

    __syncthreads();                      // reuse As as float[128][2]
    float* dred = (float*)As;
    #pragma unroll
    for (int m = 0; m < 4; ++m) {
        float dpart = 0.f;
        #pragma unroll
        for (int q = 0; q < 4; ++q) {
            int col = wc * 64 + q * 16 + lq * 4;
            float4 bb = *(const float4*)&bias[col];
            float4 wv = *(const float4*)&dotw[col];
            dpart += fmaxf(acc[m][q][0] + bb.x, 0.f) * wv.x
                   + fmaxf(acc[m][q][1] + bb.y, 0.f) * wv.y
                   + fmaxf(acc[m][q][2] + bb.z, 0.f) * wv.z
                   + fmaxf(acc[m][q][3] + bb.w, 0.f) * wv.w;
        }
        dpart += __shfl_xor(dpart, 16);
        dpart += __shfl_xor(dpart, 32);
        if (lane < 16) dred[(wr * 64 + m * 16 + lane) * 2 + wc] = dpart;
    }
    __syncthreads();
    if (tid < 128) {
        int row = brow + tid;
        if (row < n) dotout[row] = dred[tid * 2 + 0] + dred[tid * 2 + 1] + dotb[0];
    }
}

// ---------------- per-graph max + softmax denom (bounds via binary search) ----------------
__global__ void k_mdenom(const float* __restrict__ s, const int* __restrict__ batch,
                         int n, float* __restrict__ m, float* __restrict__ denom) {
    int g = blockIdx.x;
    int t = threadIdx.x;
    int i0 = lbound(batch, n, g);
    int i1 = lbound(batch, n, g + 1);
    __shared__ float red[256];
    float mx = -INFINITY;
    for (int i = i0 + t; i < i1; i += 256) mx = fmaxf(mx, s[i]);
    red[t] = mx; __syncthreads();
    for (int st = 128; st; st >>= 1) {
        if (t < st) red[t] = fmaxf(red[t], red[t + st]);
        __syncthreads();
    }
    float gm = red[0];
    __syncthreads();
    float sm = 0.f;
    for (int i = i0 + t; i < i1; i += 256) sm += expf(s[i] - gm);
    red[t] = sm; __syncthreads();
    for (int st = 128; st; st >>= 1) {
        if (t < st) red[t] += red[t + st];
        __syncthreads();
    }
    if (t == 0) { m[g] = gm; denom[g] = red[0]; }
}

// ---------------- attention pooling: per-(g,sp) partial, no atomics ----------------
__global__ void k_pool(const u16* __restrict__ h, const float* __restrict__ sarr,
                       const float* __restrict__ marr, const float* __restrict__ denom,
                       const int* __restrict__ batch, int n, int G,
                       float* __restrict__ gpool16) {
    int g = blockIdx.x, sp = blockIdx.y, t = threadIdx.x;
    int i0 = lbound(batch, n, g);
    int i1 = lbound(batch, n, g + 1);
    int len = i1 - i0;
    int a = i0 + (int)((long long)len * sp / 16);
    int b = i0 + (int)((long long)len * (sp + 1) / 16);
    float dn = denom[g];
    float inv = (dn > 0.f) ? 1.0f / dn : 0.f;
    float mg = marr[g];
    float acc = 0.f;
    for (int i = a; i < b; ++i)
        acc += expf(sarr[i] - mg) * inv * bf2f(h[(size_t)i * HID + t]);
    gpool16[((size_t)sp * G + g) * HID + t] = acc;
}

// ---------------- graph head (sums the 16 pool partials on load) ----------------
__global__ void k_ghead(const float* __restrict__ gpool16, int G,
                        const float* __restrict__ W1, const float* __restrict__ b1,
                        const float* __restrict__ W2, const float* __restrict__ b2,
                        float* __restrict__ out) {
    int g = blockIdx.x, t = threadIdx.x;  // 128 threads
    __shared__ float row[HID];
    __shared__ float red[128];
    float v0 = 0.f, v1 = 0.f;
    for (int sp = 0; sp < 16; ++sp) {
        const float* p = gpool16 + ((size_t)sp * G + g) * HID;
        v0 += p[t];
        v1 += p[t + 128];
    }
    row[t] = v0;
    row[t + 128] = v1;
    __syncthreads();
    float acc = 0.f;
    #pragma unroll 8
    for (int k = 0; k < HID; ++k) acc = fmaf(row[k], W1[k * HHALF + t], acc);
    float hid = fmaxf(acc + b1[t], 0.f);
    red[t] = hid * W2[t];
    __syncthreads();
    for (int st = 64; st; st >>= 1) {
        if (t < st) red[t] += red[t + st];
        __syncthreads();
    }
    if (t == 0) out[g] = red[0] + b2[0];
}

extern "C" void kernel_launch(void* const* d_in, const int* in_sizes, int n_in,
                              void* d_out, int out_size, void* d_ws, size_t ws_size,
                              hipStream_t stream) {
    const float* x      = (const float*)d_in[0];
    const int*   eidx   = (const int*)d_in[1];
    const int*   batch  = (const int*)d_in[2];
    const float* Ws     = (const float*)d_in[3];
    const float* Wn     = (const float*)d_in[4];
    const float* bs     = (const float*)d_in[5];
    const float* att_w  = (const float*)d_in[6];
    const float* att_b  = (const float*)d_in[7];
    const float* ne_W1  = (const float*)d_in[8];
    const float* ne_b1  = (const float*)d_in[9];
    const float* ne_W2  = (const float*)d_in[10];
    const float* ne_b2  = (const float*)d_in[11];
    const float* nd_W1  = (const float*)d_in[12];
    const float* nd_b1  = (const float*)d_in[13];
    const float* nd_W2  = (const float*)d_in[14];
    const float* nd_b2  = (const float*)d_in[15];
    float* out = (float*)d_out;

    const int N = in_sizes[2];
    const int E = in_sizes[1] / 2;
    const int L = in_sizes[3] / (HID * HID);
    const int G = out_size - N;

    const int* src = eidx;
    const int* dst = eidx + E;

    size_t off = 0;
    auto alloc = [&](size_t bytes) {
        void* p = (char*)d_ws + off;
        off += (bytes + 255) & ~(size_t)255;
        return p;
    };
    int*   cnt     = (int*)alloc((size_t)N * 4);
    int*   row_off = (int*)alloc((size_t)(N + 1) * 4);
    int*   col     = (int*)alloc((size_t)E * 4);
    int*   bsum    = (int*)alloc(1024 * 4);
    float* sarr    = (float*)alloc((size_t)N * 4);
    float* marr    = (float*)alloc((size_t)G * 4);
    float* denom   = (float*)alloc((size_t)G * 4);
    float* gpool16 = (float*)alloc((size_t)16 * G * HID * 4);
    u16*   xb      = (u16*)alloc((size_t)N * HID * 2);
    u16*   msgb    = (u16*)alloc((size_t)N * HID * 2);
    u16*   hb1     = (u16*)alloc((size_t)N * HID * 2);
    u16*   hb2     = (u16*)alloc((size_t)N * HID * 2);
    u16*   WsT     = (u16*)alloc((size_t)L * HID * HID * 2);
    u16*   WnT     = (u16*)alloc((size_t)L * HID * HID * 2);
    u16*   ndW1T   = (u16*)alloc((size_t)HID * HID * 2);  // only first 128 rows valid
    (void)ws_size;

    const int eb = (E + 255) / 256;
    const int nb = (N + 255) / 256;

    // ---- CSR build (fill-free: scatter consumes cnt) ----
    hipMemsetAsync(cnt, 0, (size_t)N * 4, stream);
    k_count<<<eb, 256, 0, stream>>>(dst, cnt, E);
    k_scan_block<<<nb, 256, 0, stream>>>(cnt, bsum, N);
    k_scan_top<<<1, 512, 0, stream>>>(bsum, nb);
    k_scan_down<<<nb, 256, 0, stream>>>(cnt, bsum, row_off, N, E);
    k_scatter<<<eb, 256, 0, stream>>>(src, dst, row_off, cnt, col, E);

    // ---- prep: x->bf16 + weight transposes, one launch ----
    const int xtotal4 = N * HID / 4;
    const int prep_blocks = (xtotal4 + 255) / 256 + (2 * L + 1) * (HID * HID / 256);
    k_prep<<<prep_blocks, 256, 0, stream>>>(
        x, xb, xtotal4, Ws, Wn, nd_W1, WsT, WnT, ndW1T, L);

    // ---- GNN layers ----
    const int gx = (N + 127) / 128;
    const u16* hin = xb;
    u16* hout = hb1;
    for (int l = 0; l < L; ++l) {
        bool last = (l == L - 1);
        k_agg<<<(N + 3) / 4, 256, 0, stream>>>(hin, row_off, col, msgb, N);
        k_gemm_bf<<<gx, 512, 0, stream>>>(
            hin, WsT + (size_t)l * HID * HID, msgb, WnT + (size_t)l * HID * HID,
            bs + (size_t)l * HID, hout, N, HID,
            last ? att_w : nullptr, last ? att_b : nullptr, last ? sarr : nullptr);
        hin = hout;
        hout = (hout == hb1) ? hb2 : hb1;
    }
    const u16* h = hin;

    // ---- attention pooling ----
    k_mdenom<<<G, 256, 0, stream>>>(sarr, batch, N, marr, denom);
    k_pool<<<dim3(G, 16), HID, 0, stream>>>(h, sarr, marr, denom, batch, N, G, gpool16);

    // ---- graph head ----
    k_ghead<<<G, HHALF, 0, stream>>>(gpool16, G, ne_W1, ne_b1, ne_W2, ne_b2, out);

    // ---- node head: dedicated 128-col fused GEMM+dot (direct store) ----
    k_ndhead<<<gx, 256, 0, stream>>>(
        h, ndW1T, nd_b1, N, nd_W2, nd_b2, out + G);
}